// Round 8
// baseline (5438.945 us; speedup 1.0000x reference)
//
#include <hip/hip_runtime.h>
#include <hip/hip_fp16.h>
#include <stdint.h>

#define B_  512
#define S_  512
#define IN_ 118
#define H1_ 256
#define H2_ 128

#define NT_  16                 // batch tiles, 32 rows each
#define NS1_ 8                  // layer-1 unit-slice blocks per tile (32 units each)
#define NS2_ 4                  // layer-2 unit-slice blocks per tile (32 units each)
#define NBLK (NT_*(NS1_+NS2_))  // 192  (< 256 CUs -> co-resident under plain launch)

// Weights are scaled by 2^10 before the fp16 hi/lo split so the lo residuals
// are NORMAL fp16. z is unscaled by the exact power of two before bias add.
#define WSCALE    1024.0f
#define WSCALE_I  0.0009765625f

typedef __attribute__((ext_vector_type(8))) short frag8;    // 8 fp16 = 4 VGPRs
typedef __attribute__((ext_vector_type(4))) float facc4;    // MFMA accumulator
typedef unsigned short u16;
typedef unsigned int   u32;

// ---------------- ws layout (bytes) ----------------
#define OFF_W1H 0
#define OFF_W1L 786432
#define OFF_W2H 1572864
#define OFF_W2L 1966080
#define OFF_AR1 2359296
#define OFF_AR2 (OFF_AR1 + 8192)
#define OFF_DN2 (OFF_AR2 + 4096)
#define OFF_HX  (OFF_AR1 + 65536)

#define A1IDX(bt,bs) ((((bt)*8+(bs))<<4))
#define A2IDX(bt,vs) ((((bt)*4+(vs))<<4))

__device__ __forceinline__ void splitf(float v, u16& hi, u16& lo) {
    __half h = __float2half(v);          // RNE
    float hf = __half2float(h);
    __half l = __float2half(v - hf);
    hi = *(u16*)&h; lo = *(u16*)&l;
}

// exact-argument exp: 2^(x*log2e) with double-float argument correction.
__device__ __forceinline__ float exp_(float x) {
    const float A  = 1.44269504f;        // fp32(log2 e)
    const float Ae = 1.9259630e-8f;      // log2(e) - (double)A
    float a = x * A;
    float e = __builtin_fmaf(x, A, -a);
    e = __builtin_fmaf(x, Ae, e);
    float p;
    asm("v_exp_f32 %0, %1" : "=v"(p) : "v"(a));
    return __builtin_fmaf(p * 0.69314718f, e, p);
}
__device__ __forceinline__ float sigm_(float x) {
    return 1.f / (1.f + exp_(fmaxf(-x, -88.f)));
}
__device__ __forceinline__ float tanh_(float x) {
    float ax = fabsf(x);
    float e  = exp_(-2.f * ax);
    float r  = (1.f - e) / (1.f + e);
    return copysignf(r, x);
}
// rsqrt with one Newton refinement (~0.5 ulp)
__device__ __forceinline__ float rsqrt_(float x) {
    float r = rsqrtf(x);
    return r * __builtin_fmaf(-0.5f * x, r * r, 1.5f);
}

// Coherence-point accesses (agent-scope relaxed atomics): bypass stale L1,
// served at the coherence point (blocks of a tile share an XCD). Ordering:
// producer's __syncthreads drains vmcnt before the flag store; consumer
// polls, barriers, then issues data loads. No wbl2/inv anywhere.
__device__ __forceinline__ u32 ld_flag(const u32* p) {
    return __hip_atomic_load(p, __ATOMIC_RELAXED, __HIP_MEMORY_SCOPE_AGENT);
}
__device__ __forceinline__ void st_flag(u32* p, u32 v) {
    __hip_atomic_store(p, v, __ATOMIC_RELAXED, __HIP_MEMORY_SCOPE_AGENT);
}
__device__ __forceinline__ float ld_coh(const float* p) {
    return __hip_atomic_load(p, __ATOMIC_RELAXED, __HIP_MEMORY_SCOPE_AGENT);
}
__device__ __forceinline__ void st_coh(float* p, float v) {
    __hip_atomic_store(p, v, __ATOMIC_RELAXED, __HIP_MEMORY_SCOPE_AGENT);
}

__global__ void prep_weights(const float* __restrict__ Wf1, const float* __restrict__ Wi1,
                             const float* __restrict__ Wg1, const float* __restrict__ Wo1,
                             const float* __restrict__ Wf2, const float* __restrict__ Wi2,
                             const float* __restrict__ Wg2, const float* __restrict__ Wo2,
                             u16* __restrict__ w1h, u16* __restrict__ w1l,
                             u16* __restrict__ w2h, u16* __restrict__ w2l) {
    int idx = blockIdx.x * 256 + threadIdx.x;
    if (idx >= 589824) return;
    if (idx < 393216) {
        int j  = idx & 7;
        int L  = (idx >> 3) & 63;
        int fr = idx >> 9;                 // tile*12 + kf
        int kf = fr % 12, tile = fr / 12;  // tile = bs*8 + ln
        int bs = tile >> 3, ln = tile & 7;
        int khat = kf*32 + (L >> 4)*8 + j;
        int lc   = ln*16 + (L & 15);
        int g = lc >> 5, unit = bs*32 + (lc & 31);
        const float* Wg[4] = {Wf1, Wi1, Wg1, Wo1};
        float v = 0.f;
        if (khat < IN_)       v = Wg[g][unit*374 + khat];        // x part
        else if (khat >= 128) v = Wg[g][unit*374 + khat - 10];   // h part (pad 118..127 = 0)
        v *= WSCALE;
        u16 hi, lo; splitf(v, hi, lo);
        w1h[idx] = hi; w1l[idx] = lo;
    } else {
        int i2 = idx - 393216;
        int j  = i2 & 7;
        int L  = (i2 >> 3) & 63;
        int fr = i2 >> 9;
        int kf = fr % 12, tile = fr / 12;  // tile = vs*8 + ln
        int vs = tile >> 3, ln = tile & 7;
        int khat = kf*32 + (L >> 4)*8 + j;
        int lc   = ln*16 + (L & 15);
        int g = lc >> 5, unit = vs*32 + (lc & 31);
        const float* Wg[4] = {Wf2, Wi2, Wg2, Wo2};
        float v = Wg[g][unit*384 + khat] * WSCALE;
        u16 hi, lo; splitf(v, hi, lo);
        w2h[i2] = hi; w2l[i2] = lo;
    }
}

// Dynamic LDS (53760 B):
//  0      combH : u16 [32][392]
//  25088  combL : u16 [32][392]
//  50176  float area: bz[128] | gamma/beta tables (896 floats)
// z overlay (scaled by WSCALE), float pitch 196/row:
//   L1: over comb cols [0,128)   -> zp[row*196 + lcl]        (x-cols, consumed pre-poll)
//   L2: over comb cols [256,384) -> zp[row*196 + 128 + lcl]  (h2-cols, read-complete at zdump)

// consumer-side LN + hi/lo split — ROUND-6-EXACT numerics: 8 active threads
// per row (tc<8), column grouping g8*64+tc*8+j, identical partial-sum trees
// and 3-level shuffle. (16th..9th thread of each row idle here: LN is cheap;
// bit-reproducibility of the recurrence matters more.)
template<int NC>   // cols per ACTIVE thread: 32 (H=256) or 16 (H=128)
__device__ __forceinline__ void build_ln(u16* combH, u16* combL, int lds_c0,
    const float* __restrict__ src, int Hstr, float invH,
    const float* sG, const float* sB, int tid, int zero)
{
    int row = tid >> 4, tc = tid & 15;
    if (tc >= 8) return;
    if (!zero) {
        const float* p = src + (size_t)row*Hstr;
        float v[NC];
        #pragma unroll
        for (int g8 = 0; g8 < NC/8; ++g8)
            #pragma unroll
            for (int j = 0; j < 8; ++j)
                v[g8*8+j] = ld_coh(&p[g8*64 + tc*8 + j]);
        float p4[NC/4];
        #pragma unroll
        for (int j = 0; j < NC/4; ++j)
            p4[j] = (v[4*j] + v[4*j+1]) + (v[4*j+2] + v[4*j+3]);
        #pragma unroll
        for (int st = 1; st < NC/4; st <<= 1)
            #pragma unroll
            for (int j = 0; j < NC/4; j += 2*st) p4[j] += p4[j+st];
        float s = p4[0];
        #pragma unroll
        for (int off = 1; off < 8; off <<= 1) s += __shfl_xor(s, off, 64);
        float mu = s * invH;
        #pragma unroll
        for (int j = 0; j < NC/4; ++j) {
            float d0 = v[4*j]   - mu, d1 = v[4*j+1] - mu;
            float d2 = v[4*j+2] - mu, d3 = v[4*j+3] - mu;
            p4[j] = (d0*d0 + d1*d1) + (d2*d2 + d3*d3);
        }
        #pragma unroll
        for (int st = 1; st < NC/4; st <<= 1)
            #pragma unroll
            for (int j = 0; j < NC/4; j += 2*st) p4[j] += p4[j+st];
        float sq = p4[0];
        #pragma unroll
        for (int off = 1; off < 8; off <<= 1) sq += __shfl_xor(sq, off, 64);
        float rs = rsqrt_(__builtin_fmaf(sq, invH, 1e-5f));
        #pragma unroll
        for (int g8 = 0; g8 < NC/8; ++g8) {
            frag8 fh, fl;
            #pragma unroll
            for (int j = 0; j < 8; ++j) {
                int u = g8*64 + tc*8 + j;
                float t_ = (v[g8*8+j] - mu)*rs;
                float hn = __builtin_fmaf(t_, sG[u], sB[u]);
                u16 hi, lo; splitf(hn, hi, lo);
                fh[j] = (short)hi; fl[j] = (short)lo;
            }
            *(frag8*)&combH[row*392 + lds_c0 + g8*64 + tc*8] = fh;
            *(frag8*)&combL[row*392 + lds_c0 + g8*64 + tc*8] = fl;
        }
    } else {
        frag8 z = {0,0,0,0,0,0,0,0};
        #pragma unroll
        for (int g8 = 0; g8 < NC/8; ++g8) {
            *(frag8*)&combH[row*392 + lds_c0 + g8*64 + tc*8] = z;
            *(frag8*)&combL[row*392 + lds_c0 + g8*64 + tc*8] = z;
        }
    }
}

// per-wave GEMM over kf range [KF0, KF1); wave owns ONE n-tile. Ascending kf
// with the fixed 4-MFMA order per kf -> identical accumulation to round 6.
template<int KF0, int KF1>
__device__ __forceinline__ void gemm_part(const u16* combH, const u16* combL,
    const frag8 (&wH)[12], const frag8 (&wL)[12], int lane, facc4 (&acc)[2])
{
    const int q = lane >> 4, cc = lane & 15;
    #pragma unroll
    for (int kf = KF0; kf < KF1; ++kf) {
        #pragma unroll
        for (int m = 0; m < 2; ++m) {
            frag8 aH = *(const frag8*)&combH[(m*16+cc)*392 + kf*32 + q*8];
            frag8 aL = *(const frag8*)&combL[(m*16+cc)*392 + kf*32 + q*8];
            acc[m] = __builtin_amdgcn_mfma_f32_16x16x32_f16(aH, wH[kf], acc[m], 0, 0, 0);
            acc[m] = __builtin_amdgcn_mfma_f32_16x16x32_f16(aL, wH[kf], acc[m], 0, 0, 0);
            acc[m] = __builtin_amdgcn_mfma_f32_16x16x32_f16(aL, wL[kf], acc[m], 0, 0, 0);
            acc[m] = __builtin_amdgcn_mfma_f32_16x16x32_f16(aH, wL[kf], acc[m], 0, 0, 0);
        }
    }
}

__device__ __forceinline__ void zdump8(u16* combH, u16* combL, int w, int lane,
                                       const facc4 (&acc)[2], int zoff)
{
    const int q = lane >> 4, cc = lane & 15;
    float* zp = (w < 4) ? (float*)combH : (float*)combL;
    int lcl = ((w & 3)*16) + cc;
    #pragma unroll
    for (int m = 0; m < 2; ++m)
        #pragma unroll
        for (int r = 0; r < 4; ++r)
            zp[(m*16 + q*4 + r)*196 + zoff + lcl] = acc[m][r];
}

__device__ __forceinline__ void gates_update8(const u16* combH, const u16* combL,
    const float* bz, float* cst, int tid, float* houtBase, int Hstr, int zoff)
{
    const float* zH = (const float*)combH + zoff;
    const float* zL = (const float*)combL + zoff;
    const int u = tid & 31, rb = tid >> 5;       // rb 0..15
    const float bzf = bz[u], bzi = bz[32+u], bzg = bz[64+u], bzo = bz[96+u];
    #pragma unroll
    for (int rr = 0; rr < 2; ++rr) {
        int row = rr*16 + rb;
        float zf = __builtin_fmaf(zH[row*196 + u],      WSCALE_I, bzf);
        float zi = __builtin_fmaf(zH[row*196 + 32 + u], WSCALE_I, bzi);
        float zg = __builtin_fmaf(zL[row*196 + u],      WSCALE_I, bzg);
        float zo = __builtin_fmaf(zL[row*196 + 32 + u], WSCALE_I, bzo);
        float ig = sigm_(zi) * tanh_(zg);
        float c  = __builtin_fmaf(sigm_(zf), cst[rr], ig);
        cst[rr]  = c;
        st_coh(&houtBase[(size_t)row*Hstr + u], sigm_(zo)*tanh_(c));
    }
}

__device__ __forceinline__ void xprefetch(const float* __restrict__ x, int b0,
                                          int t, int tid, float (&xv)[8])
{
    int row = tid >> 4, tc = tid & 15;
    const float* xp = &x[((size_t)(b0+row)*S_ + t)*IN_];
    #pragma unroll
    for (int j = 0; j < 8; ++j) {
        int col = tc*8 + j;
        xv[j] = (col < IN_) ? xp[col] : 0.f;
    }
}

__global__ __launch_bounds__(512, 2) void lstm_seq(
    const float* __restrict__ x,
    const float* __restrict__ bf1, const float* __restrict__ bi1,
    const float* __restrict__ bg1, const float* __restrict__ bo1,
    const float* __restrict__ bf2, const float* __restrict__ bi2,
    const float* __restrict__ bg2, const float* __restrict__ bo2,
    const float* __restrict__ gamma1, const float* __restrict__ beta1,
    const float* __restrict__ gamma2, const float* __restrict__ beta2,
    const u16* __restrict__ w1h, const u16* __restrict__ w1l,
    const u16* __restrict__ w2h, const u16* __restrict__ w2l,
    float* __restrict__ h1x, float* __restrict__ h2x,
    u32* __restrict__ a1, u32* __restrict__ a2, u32* __restrict__ dn2,
    int R, float* __restrict__ out)
{
    extern __shared__ char smem[];
    u16*   combH = (u16*)smem;
    u16*   combL = (u16*)(smem + 25088);
    float* fA    = (float*)(smem + 50176);
    const int tid  = threadIdx.x;
    const int w    = tid >> 6;           // wave 0..7 = n-tile
    const int lane = tid & 63;

    // XCD-local tile mapping: hw blocks round-robin XCDs (bid%8). All 12
    // blocks of a tile share one XCD: xcd k hosts tiles k and k+8.
    const int bhw  = blockIdx.x;
    const int xcd  = bhw & 7, slot = bhw >> 3;      // slot 0..23
    const int grp  = (slot >= 12) ? 1 : 0;
    const int sl   = slot - grp*12;                 // 0..11
    const int bt   = xcd + 8*grp;                   // tile 0..15
    const int b0   = bt * 32;

    if (sl < 8) {
        // ============ LAYER 1 : units [bs*32,+32), rows [b0,+32) ============
        const int bs = sl;
        float* bz = fA;           // [128]
        float* sG = fA + 128;     // gamma1 [256]
        float* sB = fA + 384;     // beta1  [256]
        if (tid < 128) {
            int g = tid >> 5, unit = bs*32 + (tid & 31);
            const float* bp = (g==0)?bf1:(g==1)?bi1:(g==2)?bg1:bo1;
            bz[tid] = bp[unit];
        }
        if (tid < 256) { sG[tid] = gamma1[tid]; sB[tid] = beta1[tid]; }
        frag8 wH[12], wL[12];        // this wave's n-tile, fully resident (96 VGPR)
        #pragma unroll
        for (int kf = 0; kf < 12; ++kf) {
            size_t base = ((((size_t)bs*8 + w)*12 + kf)*64 + lane)*8;
            wH[kf] = *(const frag8*)&w1h[base];
            wL[kf] = *(const frag8*)&w1l[base];
        }
        float cst[2] = {0.f, 0.f};   // c-state in registers for whole sequence
        float xv[8];
        xprefetch(x, b0, 0, tid, xv);
        __syncthreads();

        int slotW = 0, slotR = 0;
        for (int t = 0; t < S_; ++t) {
            // ---- x-build from prefetched regs -> comb cols [0,128)
            {
                int row = tid >> 4, tc = tid & 15;
                frag8 fh, fl;
                #pragma unroll
                for (int j = 0; j < 8; ++j) {
                    u16 hi, lo; splitf(xv[j], hi, lo);
                    fh[j] = (short)hi; fl[j] = (short)lo;
                }
                *(frag8*)&combH[row*392 + tc*8] = fh;
                *(frag8*)&combL[row*392 + tc*8] = fl;
            }
            __syncthreads();                                     // (1) x visible
            facc4 acc[2];
            acc[0] = (facc4){0.f,0.f,0.f,0.f}; acc[1] = (facc4){0.f,0.f,0.f,0.f};
            gemm_part<0,4>(combH, combL, wH, wL, lane, acc);     // x-GEMM: no deps
            {   // poll AFTER x-GEMM: sibling flags/data have propagated
                u32 need = 0; u32* p = nullptr;
                if (tid < 8 && t > 0)                    { p = &a1[A1IDX(bt, tid)];    need = (u32)t; }
                else if (tid >= 8 && tid < 12 && t >= R) { p = &dn2[A2IDX(bt, tid-8)]; need = (u32)(t - R + 1); }
                if (need) while (ld_flag(p) < need) {}
            }
            __syncthreads();                                     // (2)
            build_ln<32>(combH, combL, 128, &h1x[((size_t)slotR*B_ + b0)*H1_], H1_,
                         1.f/H1_, sG, sB, tid, t == 0);
            __syncthreads();                                     // (3)
            gemm_part<4,12>(combH, combL, wH, wL, lane, acc);    // h-GEMM (acc carried)
            zdump8(combH, combL, w, lane, acc, 0);               // overlay [0,128): disjoint
            __syncthreads();                                     // (4)
            gates_update8(combH, combL, bz, cst, tid,
                          &h1x[((size_t)slotW*B_ + b0)*H1_ + bs*32], H1_, 0);
            if (t + 1 < S_) xprefetch(x, b0, t+1, tid, xv);      // drains with stores below
            __syncthreads();                                     // (5) vmcnt drain
            if (tid == 0) st_flag(&a1[A1IDX(bt, bs)], (u32)(t + 1));
            slotR = slotW; slotW = (slotW + 1 == R) ? 0 : slotW + 1;
        }
    } else {
        // ============ LAYER 2 : units [vs*32,+32), rows [b0,+32) ============
        const int vs = sl - 8;
        float* bz  = fA;            // [128]
        float* sG1 = fA + 128;      // gamma1 [256]
        float* sB1 = fA + 384;
        float* sG2 = fA + 640;      // gamma2 [128]
        float* sB2 = fA + 768;
        if (tid < 128) {
            int g = tid >> 5, unit = vs*32 + (tid & 31);
            const float* bp = (g==0)?bf2:(g==1)?bi2:(g==2)?bg2:bo2;
            bz[tid] = bp[unit];
        }
        if (tid < 256) { sG1[tid] = gamma1[tid]; sB1[tid] = beta1[tid]; }
        if (tid < 128) { sG2[tid] = gamma2[tid]; sB2[tid] = beta2[tid]; }
        frag8 wH[12], wL[12];
        #pragma unroll
        for (int kf = 0; kf < 12; ++kf) {
            size_t base = ((((size_t)vs*8 + w)*12 + kf)*64 + lane)*8;
            wH[kf] = *(const frag8*)&w2h[base];
            wL[kf] = *(const frag8*)&w2l[base];
        }
        float cst[2] = {0.f, 0.f};
        __syncthreads();

        int slotW = 0, slotR = 0, slot1 = 0;
        for (int t = 0; t < S_; ++t) {
            // ---- h2[t-1] first (published last step — usually ready)
            if (tid < 4 && t > 0) { u32* p = &a2[A2IDX(bt, tid)]; while (ld_flag(p) < (u32)t) {} }
            __syncthreads();                                     // (1)
            build_ln<16>(combH, combL, 256, &h2x[((size_t)slotR*B_ + b0)*H2_], H2_,
                         1.f/H2_, sG2, sB2, tid, t == 0);
            // poll h1[t] while other waves finish the h2 build
            if (tid < 8) { u32* p = &a1[A1IDX(bt, tid)]; while (ld_flag(p) < (u32)(t+1)) {} }
            __syncthreads();                                     // (2)
            build_ln<32>(combH, combL, 0, &h1x[((size_t)slot1*B_ + b0)*H1_], H1_,
                         1.f/H1_, sG1, sB1, tid, 0);
            __syncthreads();                                     // (3) h1 reads complete
            if (tid == 0) st_flag(&dn2[A2IDX(bt, vs)], (u32)(t + 1));  // h1 slot consumed
            facc4 acc[2];
            acc[0] = (facc4){0.f,0.f,0.f,0.f}; acc[1] = (facc4){0.f,0.f,0.f,0.f};
            gemm_part<0,12>(combH, combL, wH, wL, lane, acc);    // full GEMM, ascending kf
            __syncthreads();                                     // (4) all reads done
            zdump8(combH, combL, w, lane, acc, 128);             // overlay [256,384)
            __syncthreads();                                     // (5)
            gates_update8(combH, combL, bz, cst, tid,
                          &h2x[((size_t)slotW*B_ + b0)*H2_ + vs*32], H2_, 128);
            __syncthreads();                                     // (6) vmcnt drain
            if (tid == 0) st_flag(&a2[A2IDX(bt, vs)], (u32)(t + 1));
            slotR = slotW; slotW = (slotW + 1 == R) ? 0 : slotW + 1;
            slot1 = (slot1 + 1 == R) ? 0 : slot1 + 1;
        }
        // ---- final output: LN(h2[511]) by slice-0 blocks (round-6-exact)
        if (vs == 0) {
            if (tid < 4) { u32* p = &a2[A2IDX(bt, tid)]; while (ld_flag(p) < (u32)S_) {} }
            __syncthreads();
            int row = tid >> 4, tc = tid & 15;
            if (tc < 8) {
                const float* p = &h2x[((size_t)slotR*B_ + b0 + row)*H2_];
                float v[16];
                #pragma unroll
                for (int g8 = 0; g8 < 2; ++g8)
                    #pragma unroll
                    for (int j = 0; j < 8; ++j)
                        v[g8*8+j] = ld_coh(&p[g8*64 + tc*8 + j]);
                float p4[4];
                #pragma unroll
                for (int j = 0; j < 4; ++j)
                    p4[j] = (v[4*j] + v[4*j+1]) + (v[4*j+2] + v[4*j+3]);
                float s = (p4[0] + p4[1]) + (p4[2] + p4[3]);
                #pragma unroll
                for (int off = 1; off < 8; off <<= 1) s += __shfl_xor(s, off, 64);
                float mu = s * (1.f/H2_);
                #pragma unroll
                for (int j = 0; j < 4; ++j) {
                    float d0 = v[4*j]   - mu, d1 = v[4*j+1] - mu;
                    float d2 = v[4*j+2] - mu, d3 = v[4*j+3] - mu;
                    p4[j] = (d0*d0 + d1*d1) + (d2*d2 + d3*d3);
                }
                float sq = (p4[0] + p4[1]) + (p4[2] + p4[3]);
                #pragma unroll
                for (int off = 1; off < 8; off <<= 1) sq += __shfl_xor(sq, off, 64);
                float rs = rsqrt_(__builtin_fmaf(sq, 1.f/H2_, 1e-5f));
                #pragma unroll
                for (int g8 = 0; g8 < 2; ++g8)
                    #pragma unroll
                    for (int j = 0; j < 8; ++j) {
                        int u = g8*64 + tc*8 + j;
                        float t_ = (v[g8*8+j]-mu)*rs;
                        out[((size_t)(b0+row))*H2_ + u] = __builtin_fmaf(t_, sG2[u], sB2[u]);
                    }
            }
        }
    }
}

extern "C" void kernel_launch(void* const* d_in, const int* in_sizes, int n_in,
                              void* d_out, int out_size, void* d_ws, size_t ws_size,
                              hipStream_t stream) {
    const float* x      = (const float*)d_in[0];
    const float* Wf1    = (const float*)d_in[1];
    const float* Wi1    = (const float*)d_in[2];
    const float* Wg1    = (const float*)d_in[3];
    const float* Wo1    = (const float*)d_in[4];
    const float* bf1    = (const float*)d_in[5];
    const float* bi1    = (const float*)d_in[6];
    const float* bg1    = (const float*)d_in[7];
    const float* bo1    = (const float*)d_in[8];
    const float* Wf2    = (const float*)d_in[9];
    const float* Wi2    = (const float*)d_in[10];
    const float* Wg2    = (const float*)d_in[11];
    const float* Wo2    = (const float*)d_in[12];
    const float* bf2    = (const float*)d_in[13];
    const float* bi2    = (const float*)d_in[14];
    const float* bg2    = (const float*)d_in[15];
    const float* bo2    = (const float*)d_in[16];
    const float* gamma1 = (const float*)d_in[17];
    const float* beta1  = (const float*)d_in[18];
    const float* gamma2 = (const float*)d_in[19];
    const float* beta2  = (const float*)d_in[20];

    char* ws = (char*)d_ws;
    u16* w1h = (u16*)(ws + OFF_W1H);
    u16* w1l = (u16*)(ws + OFF_W1L);
    u16* w2h = (u16*)(ws + OFF_W2H);
    u16* w2l = (u16*)(ws + OFF_W2L);
    u32* a1  = (u32*)(ws + OFF_AR1);
    u32* a2  = (u32*)(ws + OFF_AR2);
    u32* dn2 = (u32*)(ws + OFF_DN2);

    // exchange-ring depth: per slot 524288 B (h1) + 262144 B (h2)
    int R = (int)((ws_size - OFF_HX) / 786432);
    if (R > 16) R = 16;
    if (R < 2)  R = 2;
    float* h1x = (float*)(ws + OFF_HX);
    float* h2x = (float*)(ws + OFF_HX + (size_t)R * 524288);

    // zero the stamped flag words
    hipMemsetAsync(ws + OFF_AR1, 0, 65536, stream);

    prep_weights<<<2304, 256, 0, stream>>>(Wf1, Wi1, Wg1, Wo1, Wf2, Wi2, Wg2, Wo2,
                                           w1h, w1l, w2h, w2l);

    // Plain launch: 192 blocks (512 thr) < 256 CUs, 1 block/CU -> co-resident.
    lstm_seq<<<dim3(NBLK), dim3(512), 53760, stream>>>(
        x, bf1, bi1, bg1, bo1, bf2, bi2, bg2, bo2,
        gamma1, beta1, gamma2, beta2,
        w1h, w1l, w2h, w2l,
        h1x, h2x, a1, a2, dn2,
        R, (float*)d_out);
}

// Round 9
// 3649.757 us; speedup vs baseline: 1.4902x; 1.4902x over previous
//
#include <hip/hip_runtime.h>
#include <hip/hip_fp16.h>
#include <stdint.h>

#define B_  512
#define S_  512
#define IN_ 118
#define H1_ 256
#define H2_ 128

#define NT_  16                 // batch tiles, 32 rows each
#define NS1_ 8                  // layer-1 unit-slice blocks per tile (32 units each)
#define NS2_ 4                  // layer-2 unit-slice blocks per tile (32 units each)
#define NBLK (NT_*(NS1_+NS2_))  // 192  (< 256 CUs -> co-resident under plain launch)

// Weights are scaled by 2^10 before the fp16 hi/lo split so the lo residuals
// are NORMAL fp16. z is unscaled by the exact power of two before bias add.
#define WSCALE    1024.0f
#define WSCALE_I  0.0009765625f

typedef __attribute__((ext_vector_type(8))) short frag8;    // 8 fp16 = 4 VGPRs
typedef __attribute__((ext_vector_type(4))) float facc4;    // MFMA accumulator
typedef unsigned short u16;
typedef unsigned int   u32;

// ---------------- ws layout (bytes) ----------------
#define OFF_W1H 0
#define OFF_W1L 786432
#define OFF_W2H 1572864
#define OFF_W2L 1966080
#define OFF_AR1 2359296
#define OFF_AR2 (OFF_AR1 + 8192)
#define OFF_DN2 (OFF_AR2 + 4096)
#define OFF_REG (OFF_AR1 + 16384)       // u32[192] xcc registration
#define OFF_HX  (OFF_AR1 + 65536)

#define A1IDX(bt,bs) ((((bt)*8+(bs))<<4))
#define A2IDX(bt,vs) ((((bt)*4+(vs))<<4))

// s_getreg imm for HW_REG_XCC_ID (id=20, offset=0, size=32): (31<<11)|20
#define GETREG_XCC 63508

__device__ __forceinline__ void splitf(float v, u16& hi, u16& lo) {
    __half h = __float2half(v);          // RNE
    float hf = __half2float(h);
    __half l = __float2half(v - hf);
    hi = *(u16*)&h; lo = *(u16*)&l;
}

// exact-argument exp: 2^(x*log2e) with double-float argument correction.
__device__ __forceinline__ float exp_(float x) {
    const float A  = 1.44269504f;        // fp32(log2 e)
    const float Ae = 1.9259630e-8f;      // log2(e) - (double)A
    float a = x * A;
    float e = __builtin_fmaf(x, A, -a);
    e = __builtin_fmaf(x, Ae, e);
    float p;
    asm("v_exp_f32 %0, %1" : "=v"(p) : "v"(a));
    return __builtin_fmaf(p * 0.69314718f, e, p);
}
__device__ __forceinline__ float sigm_(float x) {
    return 1.f / (1.f + exp_(fmaxf(-x, -88.f)));
}
__device__ __forceinline__ float tanh_(float x) {
    float ax = fabsf(x);
    float e  = exp_(-2.f * ax);
    float r  = (1.f - e) / (1.f + e);
    return copysignf(r, x);
}
// rsqrt with one Newton refinement (~0.5 ulp)
__device__ __forceinline__ float rsqrt_(float x) {
    float r = rsqrtf(x);
    return r * __builtin_fmaf(-0.5f * x, r * r, 1.5f);
}

// MALL-coherent accesses (agent-scope relaxed atomics) — used for flags
// always, and for data on the fallback path (mixed-XCD tile).
__device__ __forceinline__ u32 ld_flag(const u32* p) {
    return __hip_atomic_load(p, __ATOMIC_RELAXED, __HIP_MEMORY_SCOPE_AGENT);
}
__device__ __forceinline__ void st_flag(u32* p, u32 v) {
    __hip_atomic_store(p, v, __ATOMIC_RELAXED, __HIP_MEMORY_SCOPE_AGENT);
}
__device__ __forceinline__ float ld_coh(const float* p) {
    return __hip_atomic_load(p, __ATOMIC_RELAXED, __HIP_MEMORY_SCOPE_AGENT);
}
__device__ __forceinline__ void st_coh(float* p, float v) {
    __hip_atomic_store(p, v, __ATOMIC_RELAXED, __HIP_MEMORY_SCOPE_AGENT);
}
// Fast-path acquire: drain, then invalidate vector L1 only (sc0). L2 stays —
// it is the shared coherence domain for the same-XCD tile. No L2 walks.
__device__ __forceinline__ void l1_inv() {
    asm volatile("s_waitcnt vmcnt(0)\n\tbuffer_inv sc0" ::: "memory");
}

__global__ void prep_weights(const float* __restrict__ Wf1, const float* __restrict__ Wi1,
                             const float* __restrict__ Wg1, const float* __restrict__ Wo1,
                             const float* __restrict__ Wf2, const float* __restrict__ Wi2,
                             const float* __restrict__ Wg2, const float* __restrict__ Wo2,
                             u16* __restrict__ w1h, u16* __restrict__ w1l,
                             u16* __restrict__ w2h, u16* __restrict__ w2l) {
    int idx = blockIdx.x * 256 + threadIdx.x;
    if (idx >= 589824) return;
    if (idx < 393216) {
        int j  = idx & 7;
        int L  = (idx >> 3) & 63;
        int fr = idx >> 9;                 // tile*12 + kf
        int kf = fr % 12, tile = fr / 12;  // tile = bs*8 + ln
        int bs = tile >> 3, ln = tile & 7;
        int khat = kf*32 + (L >> 4)*8 + j;
        int lc   = ln*16 + (L & 15);
        int g = lc >> 5, unit = bs*32 + (lc & 31);
        const float* Wg[4] = {Wf1, Wi1, Wg1, Wo1};
        float v = 0.f;
        if (khat < IN_)       v = Wg[g][unit*374 + khat];        // x part
        else if (khat >= 128) v = Wg[g][unit*374 + khat - 10];   // h part (pad 118..127 = 0)
        v *= WSCALE;
        u16 hi, lo; splitf(v, hi, lo);
        w1h[idx] = hi; w1l[idx] = lo;
    } else {
        int i2 = idx - 393216;
        int j  = i2 & 7;
        int L  = (i2 >> 3) & 63;
        int fr = i2 >> 9;
        int kf = fr % 12, tile = fr / 12;  // tile = vs*8 + ln
        int vs = tile >> 3, ln = tile & 7;
        int khat = kf*32 + (L >> 4)*8 + j;
        int lc   = ln*16 + (L & 15);
        int g = lc >> 5, unit = vs*32 + (lc & 31);
        const float* Wg[4] = {Wf2, Wi2, Wg2, Wo2};
        float v = Wg[g][unit*384 + khat] * WSCALE;
        u16 hi, lo; splitf(v, hi, lo);
        w2h[i2] = hi; w2l[i2] = lo;
    }
}

// Dynamic LDS (53776 B):
//  0      combH : u16 [32][392]
//  25088  combL : u16 [32][392]
//  50176  float area: bz[128] | gamma/beta tables (896 floats)
//  53760  sFast : int (per-tile fast-path flag broadcast)
// z overlay (scaled by WSCALE), float pitch 196/row:
//   L1: floats [0,64)+0   (u16 cols [0,128) = consumed x-region)
//   L2: floats [0,64)+128 (u16 cols [256,384) — written post-GEMM-barrier)

// consumer-side LN + hi/lo split — ROUND-6-EXACT numerics (8 active threads
// per row, g8*64+tc*8+j grouping, identical trees). `fast` selects plain
// cached loads (same-XCD L2, after l1_inv) vs agent-atomic MALL loads.
// Both return identical bits -> LN bit-identical either way.
template<int NC>   // cols per ACTIVE thread: 32 (H=256) or 16 (H=128)
__device__ __forceinline__ void build_ln(u16* combH, u16* combL, int lds_c0,
    const float* __restrict__ src, int Hstr, float invH,
    const float* sG, const float* sB, int tid, int zero, int fast)
{
    int row = tid >> 4, tc = tid & 15;
    if (tc >= 8) return;
    if (!zero) {
        const float* p = src + (size_t)row*Hstr;
        float v[NC];
        if (fast) {
            #pragma unroll
            for (int g8 = 0; g8 < NC/8; ++g8)
                #pragma unroll
                for (int j = 0; j < 8; ++j)
                    v[g8*8+j] = p[g8*64 + tc*8 + j];
        } else {
            #pragma unroll
            for (int g8 = 0; g8 < NC/8; ++g8)
                #pragma unroll
                for (int j = 0; j < 8; ++j)
                    v[g8*8+j] = ld_coh(&p[g8*64 + tc*8 + j]);
        }
        float p4[NC/4];
        #pragma unroll
        for (int j = 0; j < NC/4; ++j)
            p4[j] = (v[4*j] + v[4*j+1]) + (v[4*j+2] + v[4*j+3]);
        #pragma unroll
        for (int st = 1; st < NC/4; st <<= 1)
            #pragma unroll
            for (int j = 0; j < NC/4; j += 2*st) p4[j] += p4[j+st];
        float s = p4[0];
        #pragma unroll
        for (int off = 1; off < 8; off <<= 1) s += __shfl_xor(s, off, 64);
        float mu = s * invH;
        #pragma unroll
        for (int j = 0; j < NC/4; ++j) {
            float d0 = v[4*j]   - mu, d1 = v[4*j+1] - mu;
            float d2 = v[4*j+2] - mu, d3 = v[4*j+3] - mu;
            p4[j] = (d0*d0 + d1*d1) + (d2*d2 + d3*d3);
        }
        #pragma unroll
        for (int st = 1; st < NC/4; st <<= 1)
            #pragma unroll
            for (int j = 0; j < NC/4; j += 2*st) p4[j] += p4[j+st];
        float sq = p4[0];
        #pragma unroll
        for (int off = 1; off < 8; off <<= 1) sq += __shfl_xor(sq, off, 64);
        float rs = rsqrt_(__builtin_fmaf(sq, invH, 1e-5f));
        #pragma unroll
        for (int g8 = 0; g8 < NC/8; ++g8) {
            frag8 fh, fl;
            #pragma unroll
            for (int j = 0; j < 8; ++j) {
                int u = g8*64 + tc*8 + j;
                float t_ = (v[g8*8+j] - mu)*rs;
                float hn = __builtin_fmaf(t_, sG[u], sB[u]);
                u16 hi, lo; splitf(hn, hi, lo);
                fh[j] = (short)hi; fl[j] = (short)lo;
            }
            *(frag8*)&combH[row*392 + lds_c0 + g8*64 + tc*8] = fh;
            *(frag8*)&combL[row*392 + lds_c0 + g8*64 + tc*8] = fl;
        }
    } else {
        frag8 z = {0,0,0,0,0,0,0,0};
        #pragma unroll
        for (int g8 = 0; g8 < NC/8; ++g8) {
            *(frag8*)&combH[row*392 + lds_c0 + g8*64 + tc*8] = z;
            *(frag8*)&combL[row*392 + lds_c0 + g8*64 + tc*8] = z;
        }
    }
}

// per-wave GEMM over kf range [KF0, KF1); wave owns ONE n-tile. Ascending kf
// with the fixed 4-MFMA order per kf -> identical accumulation to round 6.
template<int KF0, int KF1>
__device__ __forceinline__ void gemm_part(const u16* combH, const u16* combL,
    const frag8 (&wH)[12], const frag8 (&wL)[12], int lane, facc4 (&acc)[2])
{
    const int q = lane >> 4, cc = lane & 15;
    #pragma unroll
    for (int kf = KF0; kf < KF1; ++kf) {
        #pragma unroll
        for (int m = 0; m < 2; ++m) {
            frag8 aH = *(const frag8*)&combH[(m*16+cc)*392 + kf*32 + q*8];
            frag8 aL = *(const frag8*)&combL[(m*16+cc)*392 + kf*32 + q*8];
            acc[m] = __builtin_amdgcn_mfma_f32_16x16x32_f16(aH, wH[kf], acc[m], 0, 0, 0);
            acc[m] = __builtin_amdgcn_mfma_f32_16x16x32_f16(aL, wH[kf], acc[m], 0, 0, 0);
            acc[m] = __builtin_amdgcn_mfma_f32_16x16x32_f16(aL, wL[kf], acc[m], 0, 0, 0);
            acc[m] = __builtin_amdgcn_mfma_f32_16x16x32_f16(aH, wL[kf], acc[m], 0, 0, 0);
        }
    }
}

__device__ __forceinline__ void zdump8(u16* combH, u16* combL, int w, int lane,
                                       const facc4 (&acc)[2], int zoff)
{
    const int q = lane >> 4, cc = lane & 15;
    float* zp = (w < 4) ? (float*)combH : (float*)combL;
    int lcl = ((w & 3)*16) + cc;
    #pragma unroll
    for (int m = 0; m < 2; ++m)
        #pragma unroll
        for (int r = 0; r < 4; ++r)
            zp[(m*16 + q*4 + r)*196 + zoff + lcl] = acc[m][r];
}

__device__ __forceinline__ void gates_update8(const u16* combH, const u16* combL,
    const float* bz, float* cst, int tid, float* houtBase, int Hstr, int zoff, int fast)
{
    const float* zH = (const float*)combH + zoff;
    const float* zL = (const float*)combL + zoff;
    const int u = tid & 31, rb = tid >> 5;       // rb 0..15
    const float bzf = bz[u], bzi = bz[32+u], bzg = bz[64+u], bzo = bz[96+u];
    #pragma unroll
    for (int rr = 0; rr < 2; ++rr) {
        int row = rr*16 + rb;
        float zf = __builtin_fmaf(zH[row*196 + u],      WSCALE_I, bzf);
        float zi = __builtin_fmaf(zH[row*196 + 32 + u], WSCALE_I, bzi);
        float zg = __builtin_fmaf(zL[row*196 + u],      WSCALE_I, bzg);
        float zo = __builtin_fmaf(zL[row*196 + 32 + u], WSCALE_I, bzo);
        float ig = sigm_(zi) * tanh_(zg);
        float c  = __builtin_fmaf(sigm_(zf), cst[rr], ig);
        cst[rr]  = c;
        float hv = sigm_(zo)*tanh_(c);
        if (fast) houtBase[(size_t)row*Hstr + u] = hv;   // write-through L1 -> XCD L2
        else      st_coh(&houtBase[(size_t)row*Hstr + u], hv);
    }
}

__device__ __forceinline__ void xprefetch(const float* __restrict__ x, int b0,
                                          int t, int tid, float (&xv)[8])
{
    int row = tid >> 4, tc = tid & 15;
    const float* xp = &x[((size_t)(b0+row)*S_ + t)*IN_];
    #pragma unroll
    for (int j = 0; j < 8; ++j) {
        int col = tc*8 + j;
        xv[j] = (col < IN_) ? xp[col] : 0.f;
    }
}

__global__ __launch_bounds__(512, 2) void lstm_seq(
    const float* __restrict__ x,
    const float* __restrict__ bf1, const float* __restrict__ bi1,
    const float* __restrict__ bg1, const float* __restrict__ bo1,
    const float* __restrict__ bf2, const float* __restrict__ bi2,
    const float* __restrict__ bg2, const float* __restrict__ bo2,
    const float* __restrict__ gamma1, const float* __restrict__ beta1,
    const float* __restrict__ gamma2, const float* __restrict__ beta2,
    const u16* __restrict__ w1h, const u16* __restrict__ w1l,
    const u16* __restrict__ w2h, const u16* __restrict__ w2l,
    float* __restrict__ h1x, float* __restrict__ h2x,
    u32* __restrict__ a1, u32* __restrict__ a2, u32* __restrict__ dn2,
    u32* __restrict__ regx, int R, float* __restrict__ out)
{
    extern __shared__ char smem[];
    u16*   combH = (u16*)smem;
    u16*   combL = (u16*)(smem + 25088);
    float* fA    = (float*)(smem + 50176);
    int*   sFast = (int*)(smem + 53760);
    const int tid  = threadIdx.x;
    const int w    = tid >> 6;           // wave 0..7 = n-tile
    const int lane = tid & 63;

    // XCD-local tile mapping: hw blocks round-robin XCDs (bid%8). All 12
    // blocks of a tile share one XCD: xcd k hosts tiles k and k+8.
    const int bhw  = blockIdx.x;
    const int xcd  = bhw & 7, slot = bhw >> 3;      // slot 0..23
    const int grp  = (slot >= 12) ? 1 : 0;
    const int sl   = slot - grp*12;                 // 0..11
    const int bt   = xcd + 8*grp;                   // tile 0..15
    const int b0   = bt * 32;

    // ---- runtime XCD verification: register actual XCC_ID, check all 12
    // tile members share one XCD. fast=1 -> L2-local data path (plain
    // stores + l1_inv + plain loads); fast=0 -> agent/MALL path (round-8).
    if (tid == 0) {
        u32 myx = ((u32)__builtin_amdgcn_s_getreg(GETREG_XCC)) & 15u;
        st_flag(&regx[bhw], myx + 1u);
        u32 x0 = 0; int ok = 1;
        #pragma unroll 1
        for (int r = 0; r < 12; ++r) {
            int mb = 8*(grp*12 + r) + xcd;
            u32 v; do { v = ld_flag(&regx[mb]); } while (v == 0u);
            if (r == 0) x0 = v; else ok &= (v == x0);
        }
        *sFast = ok;
    }

    if (sl < 8) {
        // ============ LAYER 1 : units [bs*32,+32), rows [b0,+32) ============
        const int bs = sl;
        float* bz = fA;           // [128]
        float* sG = fA + 128;     // gamma1 [256]
        float* sB = fA + 384;     // beta1  [256]
        if (tid < 128) {
            int g = tid >> 5, unit = bs*32 + (tid & 31);
            const float* bp = (g==0)?bf1:(g==1)?bi1:(g==2)?bg1:bo1;
            bz[tid] = bp[unit];
        }
        if (tid < 256) { sG[tid] = gamma1[tid]; sB[tid] = beta1[tid]; }
        frag8 wH[12], wL[12];        // this wave's n-tile, fully resident (96 VGPR)
        #pragma unroll
        for (int kf = 0; kf < 12; ++kf) {
            size_t base = ((((size_t)bs*8 + w)*12 + kf)*64 + lane)*8;
            wH[kf] = *(const frag8*)&w1h[base];
            wL[kf] = *(const frag8*)&w1l[base];
        }
        float cst[2] = {0.f, 0.f};   // c-state in registers for whole sequence
        float xv[8];
        xprefetch(x, b0, 0, tid, xv);
        __syncthreads();
        const int fast = *sFast;

        int slotW = 0, slotR = 0;
        for (int t = 0; t < S_; ++t) {
            // ---- x-build from prefetched regs -> comb cols [0,128)
            {
                int row = tid >> 4, tc = tid & 15;
                frag8 fh, fl;
                #pragma unroll
                for (int j = 0; j < 8; ++j) {
                    u16 hi, lo; splitf(xv[j], hi, lo);
                    fh[j] = (short)hi; fl[j] = (short)lo;
                }
                *(frag8*)&combH[row*392 + tc*8] = fh;
                *(frag8*)&combL[row*392 + tc*8] = fl;
            }
            __syncthreads();                                     // (1) x visible
            facc4 acc[2];
            acc[0] = (facc4){0.f,0.f,0.f,0.f}; acc[1] = (facc4){0.f,0.f,0.f,0.f};
            gemm_part<0,4>(combH, combL, wH, wL, lane, acc);     // x-GEMM: no deps
            {   // poll AFTER x-GEMM: sibling flags/data have propagated
                u32 need = 0; u32* p = nullptr;
                if (tid < 8 && t > 0)                    { p = &a1[A1IDX(bt, tid)];    need = (u32)t; }
                else if (tid >= 8 && tid < 12 && t >= R) { p = &dn2[A2IDX(bt, tid-8)]; need = (u32)(t - R + 1); }
                if (need) while (ld_flag(p) < need) {}
            }
            __syncthreads();                                     // (2)
            if (fast) l1_inv();                                  // acquire: inv L1 only
            build_ln<32>(combH, combL, 128, &h1x[((size_t)slotR*B_ + b0)*H1_], H1_,
                         1.f/H1_, sG, sB, tid, t == 0, fast);
            __syncthreads();                                     // (3)
            gemm_part<4,12>(combH, combL, wH, wL, lane, acc);    // h-GEMM (acc carried)
            zdump8(combH, combL, w, lane, acc, 0);               // floats [0,64): x-region only
            __syncthreads();                                     // (4)
            gates_update8(combH, combL, bz, cst, tid,
                          &h1x[((size_t)slotW*B_ + b0)*H1_ + bs*32], H1_, 0, fast);
            if (t + 1 < S_) xprefetch(x, b0, t+1, tid, xv);      // drains with stores below
            __syncthreads();                                     // (5) vmcnt drain
            if (tid == 0) st_flag(&a1[A1IDX(bt, bs)], (u32)(t + 1));
            slotR = slotW; slotW = (slotW + 1 == R) ? 0 : slotW + 1;
        }
    } else {
        // ============ LAYER 2 : units [vs*32,+32), rows [b0,+32) ============
        const int vs = sl - 8;
        float* bz  = fA;            // [128]
        float* sG1 = fA + 128;      // gamma1 [256]
        float* sB1 = fA + 384;
        float* sG2 = fA + 640;      // gamma2 [128]
        float* sB2 = fA + 768;
        if (tid < 128) {
            int g = tid >> 5, unit = vs*32 + (tid & 31);
            const float* bp = (g==0)?bf2:(g==1)?bi2:(g==2)?bg2:bo2;
            bz[tid] = bp[unit];
        }
        if (tid < 256) { sG1[tid] = gamma1[tid]; sB1[tid] = beta1[tid]; }
        if (tid < 128) { sG2[tid] = gamma2[tid]; sB2[tid] = beta2[tid]; }
        frag8 wH[12], wL[12];
        #pragma unroll
        for (int kf = 0; kf < 12; ++kf) {
            size_t base = ((((size_t)vs*8 + w)*12 + kf)*64 + lane)*8;
            wH[kf] = *(const frag8*)&w2h[base];
            wL[kf] = *(const frag8*)&w2l[base];
        }
        float cst[2] = {0.f, 0.f};
        __syncthreads();
        const int fast = *sFast;

        int slotW = 0, slotR = 0, slot1 = 0;
        for (int t = 0; t < S_; ++t) {
            // ---- h2[t-1] first (published last step — usually ready)
            if (tid < 4 && t > 0) { u32* p = &a2[A2IDX(bt, tid)]; while (ld_flag(p) < (u32)t) {} }
            __syncthreads();                                     // (1)
            if (fast) l1_inv();
            build_ln<16>(combH, combL, 256, &h2x[((size_t)slotR*B_ + b0)*H2_], H2_,
                         1.f/H2_, sG2, sB2, tid, t == 0, fast);
            // poll h1[t] while other waves finish the h2 build
            if (tid < 8) { u32* p = &a1[A1IDX(bt, tid)]; while (ld_flag(p) < (u32)(t+1)) {} }
            __syncthreads();                                     // (2)
            if (fast) l1_inv();
            build_ln<32>(combH, combL, 0, &h1x[((size_t)slot1*B_ + b0)*H1_], H1_,
                         1.f/H1_, sG1, sB1, tid, 0, fast);
            __syncthreads();                                     // (3) h1 reads complete
            if (tid == 0) st_flag(&dn2[A2IDX(bt, vs)], (u32)(t + 1));  // h1 slot consumed
            facc4 acc[2];
            acc[0] = (facc4){0.f,0.f,0.f,0.f}; acc[1] = (facc4){0.f,0.f,0.f,0.f};
            gemm_part<0,12>(combH, combL, wH, wL, lane, acc);    // full GEMM, ascending kf
            __syncthreads();                                     // (4) all reads done
            zdump8(combH, combL, w, lane, acc, 128);             // floats [128,192) = h2 cols
            __syncthreads();                                     // (5)
            gates_update8(combH, combL, bz, cst, tid,
                          &h2x[((size_t)slotW*B_ + b0)*H2_ + vs*32], H2_, 128, fast);
            __syncthreads();                                     // (6) vmcnt drain
            if (tid == 0) st_flag(&a2[A2IDX(bt, vs)], (u32)(t + 1));
            slotR = slotW; slotW = (slotW + 1 == R) ? 0 : slotW + 1;
            slot1 = (slot1 + 1 == R) ? 0 : slot1 + 1;
        }
        // ---- final output: LN(h2[511]) by slice-0 blocks (round-6-exact)
        if (vs == 0) {
            if (tid < 4) { u32* p = &a2[A2IDX(bt, tid)]; while (ld_flag(p) < (u32)S_) {} }
            __syncthreads();
            int row = tid >> 4, tc = tid & 15;
            if (tc < 8) {
                const float* p = &h2x[((size_t)slotR*B_ + b0 + row)*H2_];
                float v[16];
                #pragma unroll
                for (int g8 = 0; g8 < 2; ++g8)
                    #pragma unroll
                    for (int j = 0; j < 8; ++j)
                        v[g8*8+j] = ld_coh(&p[g8*64 + tc*8 + j]);
                float p4[4];
                #pragma unroll
                for (int j = 0; j < 4; ++j)
                    p4[j] = (v[4*j] + v[4*j+1]) + (v[4*j+2] + v[4*j+3]);
                float s = (p4[0] + p4[1]) + (p4[2] + p4[3]);
                #pragma unroll
                for (int off = 1; off < 8; off <<= 1) s += __shfl_xor(s, off, 64);
                float mu = s * (1.f/H2_);
                #pragma unroll
                for (int j = 0; j < 4; ++j) {
                    float d0 = v[4*j]   - mu, d1 = v[4*j+1] - mu;
                    float d2 = v[4*j+2] - mu, d3 = v[4*j+3] - mu;
                    p4[j] = (d0*d0 + d1*d1) + (d2*d2 + d3*d3);
                }
                float sq = (p4[0] + p4[1]) + (p4[2] + p4[3]);
                #pragma unroll
                for (int off = 1; off < 8; off <<= 1) sq += __shfl_xor(sq, off, 64);
                float rs = rsqrt_(__builtin_fmaf(sq, 1.f/H2_, 1e-5f));
                #pragma unroll
                for (int g8 = 0; g8 < 2; ++g8)
                    #pragma unroll
                    for (int j = 0; j < 8; ++j) {
                        int u = g8*64 + tc*8 + j;
                        float t_ = (v[g8*8+j]-mu)*rs;
                        out[((size_t)(b0+row))*H2_ + u] = __builtin_fmaf(t_, sG2[u], sB2[u]);
                    }
            }
        }
    }
}

extern "C" void kernel_launch(void* const* d_in, const int* in_sizes, int n_in,
                              void* d_out, int out_size, void* d_ws, size_t ws_size,
                              hipStream_t stream) {
    const float* x      = (const float*)d_in[0];
    const float* Wf1    = (const float*)d_in[1];
    const float* Wi1    = (const float*)d_in[2];
    const float* Wg1    = (const float*)d_in[3];
    const float* Wo1    = (const float*)d_in[4];
    const float* bf1    = (const float*)d_in[5];
    const float* bi1    = (const float*)d_in[6];
    const float* bg1    = (const float*)d_in[7];
    const float* bo1    = (const float*)d_in[8];
    const float* Wf2    = (const float*)d_in[9];
    const float* Wi2    = (const float*)d_in[10];
    const float* Wg2    = (const float*)d_in[11];
    const float* Wo2    = (const float*)d_in[12];
    const float* bf2    = (const float*)d_in[13];
    const float* bi2    = (const float*)d_in[14];
    const float* bg2    = (const float*)d_in[15];
    const float* bo2    = (const float*)d_in[16];
    const float* gamma1 = (const float*)d_in[17];
    const float* beta1  = (const float*)d_in[18];
    const float* gamma2 = (const float*)d_in[19];
    const float* beta2  = (const float*)d_in[20];

    char* ws = (char*)d_ws;
    u16* w1h = (u16*)(ws + OFF_W1H);
    u16* w1l = (u16*)(ws + OFF_W1L);
    u16* w2h = (u16*)(ws + OFF_W2H);
    u16* w2l = (u16*)(ws + OFF_W2L);
    u32* a1  = (u32*)(ws + OFF_AR1);
    u32* a2  = (u32*)(ws + OFF_AR2);
    u32* dn2 = (u32*)(ws + OFF_DN2);
    u32* regx= (u32*)(ws + OFF_REG);

    // exchange-ring depth: per slot 524288 B (h1) + 262144 B (h2)
    int R = (int)((ws_size - OFF_HX) / 786432);
    if (R > 16) R = 16;
    if (R < 2)  R = 2;
    float* h1x = (float*)(ws + OFF_HX);
    float* h2x = (float*)(ws + OFF_HX + (size_t)R * 524288);

    // zero the stamped flag words + registration area
    hipMemsetAsync(ws + OFF_AR1, 0, 65536, stream);

    prep_weights<<<2304, 256, 0, stream>>>(Wf1, Wi1, Wg1, Wo1, Wf2, Wi2, Wg2, Wo2,
                                           w1h, w1l, w2h, w2l);

    // Plain launch: 192 blocks (512 thr) < 256 CUs, 1 block/CU -> co-resident.
    lstm_seq<<<dim3(NBLK), dim3(512), 53776, stream>>>(
        x, bf1, bi1, bg1, bo1, bf2, bi2, bg2, bo2,
        gamma1, beta1, gamma2, beta2,
        w1h, w1l, w2h, w2l,
        h1x, h2x, a1, a2, dn2, regx,
        R, (float*)d_out);
}

// Round 12
// 3644.097 us; speedup vs baseline: 1.4925x; 1.0016x over previous
//
#include <hip/hip_runtime.h>
#include <hip/hip_fp16.h>
#include <stdint.h>

#define B_  512
#define S_  512
#define IN_ 118
#define H1_ 256
#define H2_ 128

#define NT_  16                 // batch tiles, 32 rows each
#define NS1_ 8                  // layer-1 unit-slice blocks per tile (32 units each)
#define NS2_ 4                  // layer-2 unit-slice blocks per tile (32 units each)
#define NBLK (NT_*(NS1_+NS2_))  // 192  (< 256 CUs -> co-resident under plain launch)

// Weights are scaled by 2^10 before the fp16 hi/lo split so the lo residuals
// are NORMAL fp16. z is unscaled by the exact power of two before bias add.
#define WSCALE    1024.0f
#define WSCALE_I  0.0009765625f

typedef __attribute__((ext_vector_type(8))) short frag8;    // 8 fp16 = 4 VGPRs
typedef __attribute__((ext_vector_type(4))) float facc4;    // MFMA accumulator
typedef unsigned short u16;
typedef unsigned int   u32;

// ---------------- ws layout (bytes) ----------------
#define OFF_W1H 0
#define OFF_W1L 786432
#define OFF_W2H 1572864
#define OFF_W2L 1966080
#define OFF_AR1 2359296
#define OFF_AR2 (OFF_AR1 + 8192)
#define OFF_DN2 (OFF_AR2 + 4096)
#define OFF_REG (OFF_AR1 + 16384)       // u32[192] xcc registration
#define OFF_HX  (OFF_AR1 + 65536)

#define A1IDX(bt,bs) ((((bt)*8+(bs))<<4))
#define A2IDX(bt,vs) ((((bt)*4+(vs))<<4))

// s_getreg imm for HW_REG_XCC_ID (id=20, offset=0, size=32): (31<<11)|20
#define GETREG_XCC 63508

// One-time pin: mark the 12 fragments as asm-defined (identity). The compiler
// can no longer rematerialize them from L2 inside the loop (rounds 6-9:
// VGPR_Count=100 < the 96 VGPRs the weights alone need -> per-step reloads).
// Executed ONCE after the load; no per-iteration effect on codegen.
#define PIN12(a) asm volatile("" : "+v"(a[0]), "+v"(a[1]), "+v"(a[2]), "+v"(a[3]), \
    "+v"(a[4]), "+v"(a[5]), "+v"(a[6]), "+v"(a[7]), "+v"(a[8]), "+v"(a[9]), \
    "+v"(a[10]), "+v"(a[11]))

__device__ __forceinline__ void splitf(float v, u16& hi, u16& lo) {
    __half h = __float2half(v);          // RNE
    float hf = __half2float(h);
    __half l = __float2half(v - hf);
    hi = *(u16*)&h; lo = *(u16*)&l;
}

// exact-argument exp: 2^(x*log2e) with double-float argument correction.
__device__ __forceinline__ float exp_(float x) {
    const float A  = 1.44269504f;        // fp32(log2 e)
    const float Ae = 1.9259630e-8f;      // log2(e) - (double)A
    float a = x * A;
    float e = __builtin_fmaf(x, A, -a);
    e = __builtin_fmaf(x, Ae, e);
    float p;
    asm("v_exp_f32 %0, %1" : "=v"(p) : "v"(a));
    return __builtin_fmaf(p * 0.69314718f, e, p);
}
__device__ __forceinline__ float sigm_(float x) {
    return 1.f / (1.f + exp_(fmaxf(-x, -88.f)));
}
__device__ __forceinline__ float tanh_(float x) {
    float ax = fabsf(x);
    float e  = exp_(-2.f * ax);
    float r  = (1.f - e) / (1.f + e);
    return copysignf(r, x);
}
// rsqrt with one Newton refinement (~0.5 ulp)
__device__ __forceinline__ float rsqrt_(float x) {
    float r = rsqrtf(x);
    return r * __builtin_fmaf(-0.5f * x, r * r, 1.5f);
}

// MALL-coherent accesses (agent-scope relaxed atomics). Flags ALWAYS use
// these (proven correct rounds 4-9; compiler emits the proper coherence
// bits for agent scope). Data uses them on the fallback (mixed-XCD) path.
__device__ __forceinline__ u32 ld_flag(const u32* p) {
    return __hip_atomic_load(p, __ATOMIC_RELAXED, __HIP_MEMORY_SCOPE_AGENT);
}
__device__ __forceinline__ void st_flag(u32* p, u32 v) {
    __hip_atomic_store(p, v, __ATOMIC_RELAXED, __HIP_MEMORY_SCOPE_AGENT);
}
__device__ __forceinline__ float ld_coh(const float* p) {
    return __hip_atomic_load(p, __ATOMIC_RELAXED, __HIP_MEMORY_SCOPE_AGENT);
}
__device__ __forceinline__ void st_coh(float* p, float v) {
    __hip_atomic_store(p, v, __ATOMIC_RELAXED, __HIP_MEMORY_SCOPE_AGENT);
}
// Fast-path acquire: drain, then invalidate vector L1 only (sc0). L2 stays —
// it is the shared coherence domain for the same-XCD tile. No L2 walks.
__device__ __forceinline__ void l1_inv() {
    asm volatile("s_waitcnt vmcnt(0)\n\tbuffer_inv sc0" ::: "memory");
}

__global__ void prep_weights(const float* __restrict__ Wf1, const float* __restrict__ Wi1,
                             const float* __restrict__ Wg1, const float* __restrict__ Wo1,
                             const float* __restrict__ Wf2, const float* __restrict__ Wi2,
                             const float* __restrict__ Wg2, const float* __restrict__ Wo2,
                             u16* __restrict__ w1h, u16* __restrict__ w1l,
                             u16* __restrict__ w2h, u16* __restrict__ w2l) {
    int idx = blockIdx.x * 256 + threadIdx.x;
    if (idx >= 589824) return;
    if (idx < 393216) {
        int j  = idx & 7;
        int L  = (idx >> 3) & 63;
        int fr = idx >> 9;                 // tile*12 + kf
        int kf = fr % 12, tile = fr / 12;  // tile = bs*8 + ln
        int bs = tile >> 3, ln = tile & 7;
        int khat = kf*32 + (L >> 4)*8 + j;
        int lc   = ln*16 + (L & 15);
        int g = lc >> 5, unit = bs*32 + (lc & 31);
        const float* Wg[4] = {Wf1, Wi1, Wg1, Wo1};
        float v = 0.f;
        if (khat < IN_)       v = Wg[g][unit*374 + khat];        // x part
        else if (khat >= 128) v = Wg[g][unit*374 + khat - 10];   // h part (pad 118..127 = 0)
        v *= WSCALE;
        u16 hi, lo; splitf(v, hi, lo);
        w1h[idx] = hi; w1l[idx] = lo;
    } else {
        int i2 = idx - 393216;
        int j  = i2 & 7;
        int L  = (i2 >> 3) & 63;
        int fr = i2 >> 9;
        int kf = fr % 12, tile = fr / 12;  // tile = vs*8 + ln
        int vs = tile >> 3, ln = tile & 7;
        int khat = kf*32 + (L >> 4)*8 + j;
        int lc   = ln*16 + (L & 15);
        int g = lc >> 5, unit = vs*32 + (lc & 31);
        const float* Wg[4] = {Wf2, Wi2, Wg2, Wo2};
        float v = Wg[g][unit*384 + khat] * WSCALE;
        u16 hi, lo; splitf(v, hi, lo);
        w2h[i2] = hi; w2l[i2] = lo;
    }
}

// Dynamic LDS (53776 B):
//  0      combH : u16 [32][392]
//  25088  combL : u16 [32][392]
//  50176  float area: bz[128] | gamma/beta tables (896 floats)
//  53760  sFast : int (per-tile fast-path flag broadcast)
// z overlay (scaled by WSCALE), float pitch 196/row:
//   L1: floats [0,64)+0   (u16 cols [0,128) = consumed x-region)
//   L2: floats [0,64)+128 (u16 cols [256,384) — written post-GEMM-barrier)

// consumer-side LN + hi/lo split — ROUND-6-EXACT numerics (8 active threads
// per row, g8*64+tc*8+j grouping, identical trees). `fast` selects plain
// cached loads (same-XCD L2, after l1_inv) vs agent-atomic MALL loads.
template<int NC>   // cols per ACTIVE thread: 32 (H=256) or 16 (H=128)
__device__ __forceinline__ void build_ln(u16* combH, u16* combL, int lds_c0,
    const float* __restrict__ src, int Hstr, float invH,
    const float* sG, const float* sB, int tid, int zero, int fast)
{
    int row = tid >> 4, tc = tid & 15;
    if (tc >= 8) return;
    if (!zero) {
        const float* p = src + (size_t)row*Hstr;
        float v[NC];
        if (fast) {
            #pragma unroll
            for (int g8 = 0; g8 < NC/8; ++g8)
                #pragma unroll
                for (int j = 0; j < 8; ++j)
                    v[g8*8+j] = p[g8*64 + tc*8 + j];
        } else {
            #pragma unroll
            for (int g8 = 0; g8 < NC/8; ++g8)
                #pragma unroll
                for (int j = 0; j < 8; ++j)
                    v[g8*8+j] = ld_coh(&p[g8*64 + tc*8 + j]);
        }
        float p4[NC/4];
        #pragma unroll
        for (int j = 0; j < NC/4; ++j)
            p4[j] = (v[4*j] + v[4*j+1]) + (v[4*j+2] + v[4*j+3]);
        #pragma unroll
        for (int st = 1; st < NC/4; st <<= 1)
            #pragma unroll
            for (int j = 0; j < NC/4; j += 2*st) p4[j] += p4[j+st];
        float s = p4[0];
        #pragma unroll
        for (int off = 1; off < 8; off <<= 1) s += __shfl_xor(s, off, 64);
        float mu = s * invH;
        #pragma unroll
        for (int j = 0; j < NC/4; ++j) {
            float d0 = v[4*j]   - mu, d1 = v[4*j+1] - mu;
            float d2 = v[4*j+2] - mu, d3 = v[4*j+3] - mu;
            p4[j] = (d0*d0 + d1*d1) + (d2*d2 + d3*d3);
        }
        #pragma unroll
        for (int st = 1; st < NC/4; st <<= 1)
            #pragma unroll
            for (int j = 0; j < NC/4; j += 2*st) p4[j] += p4[j+st];
        float sq = p4[0];
        #pragma unroll
        for (int off = 1; off < 8; off <<= 1) sq += __shfl_xor(sq, off, 64);
        float rs = rsqrt_(__builtin_fmaf(sq, invH, 1e-5f));
        #pragma unroll
        for (int g8 = 0; g8 < NC/8; ++g8) {
            frag8 fh, fl;
            #pragma unroll
            for (int j = 0; j < 8; ++j) {
                int u = g8*64 + tc*8 + j;
                float t_ = (v[g8*8+j] - mu)*rs;
                float hn = __builtin_fmaf(t_, sG[u], sB[u]);
                u16 hi, lo; splitf(hn, hi, lo);
                fh[j] = (short)hi; fl[j] = (short)lo;
            }
            *(frag8*)&combH[row*392 + lds_c0 + g8*64 + tc*8] = fh;
            *(frag8*)&combL[row*392 + lds_c0 + g8*64 + tc*8] = fl;
        }
    } else {
        frag8 z = {0,0,0,0,0,0,0,0};
        #pragma unroll
        for (int g8 = 0; g8 < NC/8; ++g8) {
            *(frag8*)&combH[row*392 + lds_c0 + g8*64 + tc*8] = z;
            *(frag8*)&combL[row*392 + lds_c0 + g8*64 + tc*8] = z;
        }
    }
}

// per-wave GEMM over kf range [KF0, KF1); wave owns ONE n-tile. Ascending kf
// with the fixed 4-MFMA order per kf -> identical accumulation to round 6.
template<int KF0, int KF1>
__device__ __forceinline__ void gemm_part(const u16* combH, const u16* combL,
    const frag8 (&wH)[12], const frag8 (&wL)[12], int lane, facc4 (&acc)[2])
{
    const int q = lane >> 4, cc = lane & 15;
    #pragma unroll
    for (int kf = KF0; kf < KF1; ++kf) {
        #pragma unroll
        for (int m = 0; m < 2; ++m) {
            frag8 aH = *(const frag8*)&combH[(m*16+cc)*392 + kf*32 + q*8];
            frag8 aL = *(const frag8*)&combL[(m*16+cc)*392 + kf*32 + q*8];
            acc[m] = __builtin_amdgcn_mfma_f32_16x16x32_f16(aH, wH[kf], acc[m], 0, 0, 0);
            acc[m] = __builtin_amdgcn_mfma_f32_16x16x32_f16(aL, wH[kf], acc[m], 0, 0, 0);
            acc[m] = __builtin_amdgcn_mfma_f32_16x16x32_f16(aL, wL[kf], acc[m], 0, 0, 0);
            acc[m] = __builtin_amdgcn_mfma_f32_16x16x32_f16(aH, wL[kf], acc[m], 0, 0, 0);
        }
    }
}

__device__ __forceinline__ void zdump8(u16* combH, u16* combL, int w, int lane,
                                       const facc4 (&acc)[2], int zoff)
{
    const int q = lane >> 4, cc = lane & 15;
    float* zp = (w < 4) ? (float*)combH : (float*)combL;
    int lcl = ((w & 3)*16) + cc;
    #pragma unroll
    for (int m = 0; m < 2; ++m)
        #pragma unroll
        for (int r = 0; r < 4; ++r)
            zp[(m*16 + q*4 + r)*196 + zoff + lcl] = acc[m][r];
}

__device__ __forceinline__ void gates_update8(const u16* combH, const u16* combL,
    const float* bz, float* cst, int tid, float* houtBase, int Hstr, int zoff, int fast)
{
    const float* zH = (const float*)combH + zoff;
    const float* zL = (const float*)combL + zoff;
    const int u = tid & 31, rb = tid >> 5;       // rb 0..15
    const float bzf = bz[u], bzi = bz[32+u], bzg = bz[64+u], bzo = bz[96+u];
    #pragma unroll
    for (int rr = 0; rr < 2; ++rr) {
        int row = rr*16 + rb;
        float zf = __builtin_fmaf(zH[row*196 + u],      WSCALE_I, bzf);
        float zi = __builtin_fmaf(zH[row*196 + 32 + u], WSCALE_I, bzi);
        float zg = __builtin_fmaf(zL[row*196 + u],      WSCALE_I, bzg);
        float zo = __builtin_fmaf(zL[row*196 + 32 + u], WSCALE_I, bzo);
        float ig = sigm_(zi) * tanh_(zg);
        float c  = __builtin_fmaf(sigm_(zf), cst[rr], ig);
        cst[rr]  = c;
        float hv = sigm_(zo)*tanh_(c);
        if (fast) houtBase[(size_t)row*Hstr + u] = hv;   // write-through L1 -> XCD L2
        else      st_coh(&houtBase[(size_t)row*Hstr + u], hv);
    }
}

__device__ __forceinline__ void xprefetch(const float* __restrict__ x, int b0,
                                          int t, int tid, float (&xv)[8])
{
    int row = tid >> 4, tc = tid & 15;
    const float* xp = &x[((size_t)(b0+row)*S_ + t)*IN_];
    #pragma unroll
    for (int j = 0; j < 8; ++j) {
        int col = tc*8 + j;
        xv[j] = (col < IN_) ? xp[col] : 0.f;
    }
}

__global__ __launch_bounds__(512, 2) void lstm_seq(
    const float* __restrict__ x,
    const float* __restrict__ bf1, const float* __restrict__ bi1,
    const float* __restrict__ bg1, const float* __restrict__ bo1,
    const float* __restrict__ bf2, const float* __restrict__ bi2,
    const float* __restrict__ bg2, const float* __restrict__ bo2,
    const float* __restrict__ gamma1, const float* __restrict__ beta1,
    const float* __restrict__ gamma2, const float* __restrict__ beta2,
    const u16* __restrict__ w1h, const u16* __restrict__ w1l,
    const u16* __restrict__ w2h, const u16* __restrict__ w2l,
    float* __restrict__ h1x, float* __restrict__ h2x,
    u32* __restrict__ a1, u32* __restrict__ a2, u32* __restrict__ dn2,
    u32* __restrict__ regx, int R, float* __restrict__ out)
{
    extern __shared__ char smem[];
    u16*   combH = (u16*)smem;
    u16*   combL = (u16*)(smem + 25088);
    float* fA    = (float*)(smem + 50176);
    int*   sFast = (int*)(smem + 53760);
    const int tid  = threadIdx.x;
    const int w    = tid >> 6;           // wave 0..7 = n-tile
    const int lane = tid & 63;

    // XCD-local tile mapping: hw blocks round-robin XCDs (bid%8). All 12
    // blocks of a tile share one XCD: xcd k hosts tiles k and k+8.
    const int bhw  = blockIdx.x;
    const int xcd  = bhw & 7, slot = bhw >> 3;      // slot 0..23
    const int grp  = (slot >= 12) ? 1 : 0;
    const int sl   = slot - grp*12;                 // 0..11
    const int bt   = xcd + 8*grp;                   // tile 0..15
    const int b0   = bt * 32;

    // ---- runtime XCD verification: register actual XCC_ID, check all 12
    // tile members share one XCD. fast=1 -> L2-local data path (plain
    // stores + l1_inv + plain loads); fast=0 -> agent/MALL path (round-8).
    if (tid == 0) {
        u32 myx = ((u32)__builtin_amdgcn_s_getreg(GETREG_XCC)) & 15u;
        st_flag(&regx[bhw], myx + 1u);
        u32 x0 = 0; int ok = 1;
        #pragma unroll 1
        for (int r = 0; r < 12; ++r) {
            int mb = 8*(grp*12 + r) + xcd;
            u32 v; do { v = ld_flag(&regx[mb]); } while (v == 0u);
            if (r == 0) x0 = v; else ok &= (v == x0);
        }
        *sFast = ok;
    }

    if (sl < 8) {
        // ============ LAYER 1 : units [bs*32,+32), rows [b0,+32) ============
        const int bs = sl;
        float* bz = fA;           // [128]
        float* sG = fA + 128;     // gamma1 [256]
        float* sB = fA + 384;     // beta1  [256]
        if (tid < 128) {
            int g = tid >> 5, unit = bs*32 + (tid & 31);
            const float* bp = (g==0)?bf1:(g==1)?bi1:(g==2)?bg1:bo1;
            bz[tid] = bp[unit];
        }
        if (tid < 256) { sG[tid] = gamma1[tid]; sB[tid] = beta1[tid]; }
        frag8 wH[12], wL[12];        // this wave's n-tile (96 VGPR, pinned resident)
        #pragma unroll
        for (int kf = 0; kf < 12; ++kf) {
            size_t base = ((((size_t)bs*8 + w)*12 + kf)*64 + lane)*8;
            wH[kf] = *(const frag8*)&w1h[base];
            wL[kf] = *(const frag8*)&w1l[base];
        }
        PIN12(wH); PIN12(wL);        // one-time: defeat in-loop rematerialization
        float cst[2] = {0.f, 0.f};   // c-state in registers for whole sequence
        float xv[8];
        xprefetch(x, b0, 0, tid, xv);
        __syncthreads();
        const int fast = *sFast;

        int slotW = 0, slotR = 0;
        for (int t = 0; t < S_; ++t) {
            // ---- x-build from prefetched regs -> comb cols [0,128)
            {
                int row = tid >> 4, tc = tid & 15;
                frag8 fh, fl;
                #pragma unroll
                for (int j = 0; j < 8; ++j) {
                    u16 hi, lo; splitf(xv[j], hi, lo);
                    fh[j] = (short)hi; fl[j] = (short)lo;
                }
                *(frag8*)&combH[row*392 + tc*8] = fh;
                *(frag8*)&combL[row*392 + tc*8] = fl;
            }
            __syncthreads();                                     // (1) x visible
            facc4 acc[2];
            acc[0] = (facc4){0.f,0.f,0.f,0.f}; acc[1] = (facc4){0.f,0.f,0.f,0.f};
            gemm_part<0,4>(combH, combL, wH, wL, lane, acc);     // x-GEMM: no deps
            {   // poll AFTER x-GEMM: sibling flags/data have propagated
                u32 need = 0; u32* p = nullptr;
                if (tid < 8 && t > 0)                    { p = &a1[A1IDX(bt, tid)];    need = (u32)t; }
                else if (tid >= 8 && tid < 12 && t >= R) { p = &dn2[A2IDX(bt, tid-8)]; need = (u32)(t - R + 1); }
                if (need) while (ld_flag(p) < need) {}
            }
            __syncthreads();                                     // (2)
            if (fast) l1_inv();                                  // acquire: inv L1 only
            build_ln<32>(combH, combL, 128, &h1x[((size_t)slotR*B_ + b0)*H1_], H1_,
                         1.f/H1_, sG, sB, tid, t == 0, fast);
            __syncthreads();                                     // (3)
            gemm_part<4,12>(combH, combL, wH, wL, lane, acc);    // h-GEMM (acc carried)
            zdump8(combH, combL, w, lane, acc, 0);               // floats [0,64): x-region only
            __syncthreads();                                     // (4)
            gates_update8(combH, combL, bz, cst, tid,
                          &h1x[((size_t)slotW*B_ + b0)*H1_ + bs*32], H1_, 0, fast);
            if (t + 1 < S_) xprefetch(x, b0, t+1, tid, xv);      // drains with stores below
            __syncthreads();                                     // (5) vmcnt drain
            if (tid == 0) st_flag(&a1[A1IDX(bt, bs)], (u32)(t + 1));
            slotR = slotW; slotW = (slotW + 1 == R) ? 0 : slotW + 1;
        }
    } else {
        // ============ LAYER 2 : units [vs*32,+32), rows [b0,+32) ============
        const int vs = sl - 8;
        float* bz  = fA;            // [128]
        float* sG1 = fA + 128;      // gamma1 [256]
        float* sB1 = fA + 384;
        float* sG2 = fA + 640;      // gamma2 [128]
        float* sB2 = fA + 768;
        if (tid < 128) {
            int g = tid >> 5, unit = vs*32 + (tid & 31);
            const float* bp = (g==0)?bf2:(g==1)?bi2:(g==2)?bg2:bo2;
            bz[tid] = bp[unit];
        }
        if (tid < 256) { sG1[tid] = gamma1[tid]; sB1[tid] = beta1[tid]; }
        if (tid < 128) { sG2[tid] = gamma2[tid]; sB2[tid] = beta2[tid]; }
        frag8 wH[12], wL[12];
        #pragma unroll
        for (int kf = 0; kf < 12; ++kf) {
            size_t base = ((((size_t)vs*8 + w)*12 + kf)*64 + lane)*8;
            wH[kf] = *(const frag8*)&w2h[base];
            wL[kf] = *(const frag8*)&w2l[base];
        }
        PIN12(wH); PIN12(wL);        // one-time: defeat in-loop rematerialization
        float cst[2] = {0.f, 0.f};
        __syncthreads();
        const int fast = *sFast;

        int slotW = 0, slotR = 0, slot1 = 0;
        for (int t = 0; t < S_; ++t) {
            // ---- h2[t-1] first (published last step — usually ready)
            if (tid < 4 && t > 0) { u32* p = &a2[A2IDX(bt, tid)]; while (ld_flag(p) < (u32)t) {} }
            __syncthreads();                                     // (1)
            if (fast) l1_inv();
            build_ln<16>(combH, combL, 256, &h2x[((size_t)slotR*B_ + b0)*H2_], H2_,
                         1.f/H2_, sG2, sB2, tid, t == 0, fast);
            // poll h1[t] while other waves finish the h2 build
            if (tid < 8) { u32* p = &a1[A1IDX(bt, tid)]; while (ld_flag(p) < (u32)(t+1)) {} }
            __syncthreads();                                     // (2)
            if (fast) l1_inv();
            build_ln<32>(combH, combL, 0, &h1x[((size_t)slot1*B_ + b0)*H1_], H1_,
                         1.f/H1_, sG1, sB1, tid, 0, fast);
            __syncthreads();                                     // (3) h1 reads complete
            if (tid == 0) st_flag(&dn2[A2IDX(bt, vs)], (u32)(t + 1));  // h1 slot consumed
            facc4 acc[2];
            acc[0] = (facc4){0.f,0.f,0.f,0.f}; acc[1] = (facc4){0.f,0.f,0.f,0.f};
            gemm_part<0,12>(combH, combL, wH, wL, lane, acc);    // full GEMM, ascending kf
            __syncthreads();                                     // (4) all reads done
            zdump8(combH, combL, w, lane, acc, 128);             // floats [128,192) = h2 cols
            __syncthreads();                                     // (5)
            gates_update8(combH, combL, bz, cst, tid,
                          &h2x[((size_t)slotW*B_ + b0)*H2_ + vs*32], H2_, 128, fast);
            __syncthreads();                                     // (6) vmcnt drain
            if (tid == 0) st_flag(&a2[A2IDX(bt, vs)], (u32)(t + 1));
            slotR = slotW; slotW = (slotW + 1 == R) ? 0 : slotW + 1;
            slot1 = (slot1 + 1 == R) ? 0 : slot1 + 1;
        }
        // ---- final output: LN(h2[511]) by slice-0 blocks (round-6-exact)
        if (vs == 0) {
            if (tid < 4) { u32* p = &a2[A2IDX(bt, tid)]; while (ld_flag(p) < (u32)S_) {} }
            __syncthreads();
            int row = tid >> 4, tc = tid & 15;
            if (tc < 8) {
                const float* p = &h2x[((size_t)slotR*B_ + b0 + row)*H2_];
                float v[16];
                #pragma unroll
                for (int g8 = 0; g8 < 2; ++g8)
                    #pragma unroll
                    for (int j = 0; j < 8; ++j)
                        v[g8*8+j] = ld_coh(&p[g8*64 + tc*8 + j]);
                float p4[4];
                #pragma unroll
                for (int j = 0; j < 4; ++j)
                    p4[j] = (v[4*j] + v[4*j+1]) + (v[4*j+2] + v[4*j+3]);
                float s = (p4[0] + p4[1]) + (p4[2] + p4[3]);
                #pragma unroll
                for (int off = 1; off < 8; off <<= 1) s += __shfl_xor(s, off, 64);
                float mu = s * (1.f/H2_);
                #pragma unroll
                for (int j = 0; j < 4; ++j) {
                    float d0 = v[4*j]   - mu, d1 = v[4*j+1] - mu;
                    float d2 = v[4*j+2] - mu, d3 = v[4*j+3] - mu;
                    p4[j] = (d0*d0 + d1*d1) + (d2*d2 + d3*d3);
                }
                float sq = (p4[0] + p4[1]) + (p4[2] + p4[3]);
                #pragma unroll
                for (int off = 1; off < 8; off <<= 1) sq += __shfl_xor(sq, off, 64);
                float rs = rsqrt_(__builtin_fmaf(sq, 1.f/H2_, 1e-5f));
                #pragma unroll
                for (int g8 = 0; g8 < 2; ++g8)
                    #pragma unroll
                    for (int j = 0; j < 8; ++j) {
                        int u = g8*64 + tc*8 + j;
                        float t_ = (v[g8*8+j]-mu)*rs;
                        out[((size_t)(b0+row))*H2_ + u] = __builtin_fmaf(t_, sG2[u], sB2[u]);
                    }
            }
        }
    }
}

extern "C" void kernel_launch(void* const* d_in, const int* in_sizes, int n_in,
                              void* d_out, int out_size, void* d_ws, size_t ws_size,
                              hipStream_t stream) {
    const float* x      = (const float*)d_in[0];
    const float* Wf1    = (const float*)d_in[1];
    const float* Wi1    = (const float*)d_in[2];
    const float* Wg1    = (const float*)d_in[3];
    const float* Wo1    = (const float*)d_in[4];
    const float* bf1    = (const float*)d_in[5];
    const float* bi1    = (const float*)d_in[6];
    const float* bg1    = (const float*)d_in[7];
    const float* bo1    = (const float*)d_in[8];
    const float* Wf2    = (const float*)d_in[9];
    const float* Wi2    = (const float*)d_in[10];
    const float* Wg2    = (const float*)d_in[11];
    const float* Wo2    = (const float*)d_in[12];
    const float* bf2    = (const float*)d_in[13];
    const float* bi2    = (const float*)d_in[14];
    const float* bg2    = (const float*)d_in[15];
    const float* bo2    = (const float*)d_in[16];
    const float* gamma1 = (const float*)d_in[17];
    const float* beta1  = (const float*)d_in[18];
    const float* gamma2 = (const float*)d_in[19];
    const float* beta2  = (const float*)d_in[20];

    char* ws = (char*)d_ws;
    u16* w1h = (u16*)(ws + OFF_W1H);
    u16* w1l = (u16*)(ws + OFF_W1L);
    u16* w2h = (u16*)(ws + OFF_W2H);
    u16* w2l = (u16*)(ws + OFF_W2L);
    u32* a1  = (u32*)(ws + OFF_AR1);
    u32* a2  = (u32*)(ws + OFF_AR2);
    u32* dn2 = (u32*)(ws + OFF_DN2);
    u32* regx= (u32*)(ws + OFF_REG);

    // exchange-ring depth: per slot 524288 B (h1) + 262144 B (h2)
    int R = (int)((ws_size - OFF_HX) / 786432);
    if (R > 16) R = 16;
    if (R < 2)  R = 2;
    float* h1x = (float*)(ws + OFF_HX);
    float* h2x = (float*)(ws + OFF_HX + (size_t)R * 524288);

    // zero the stamped flag words + registration area
    hipMemsetAsync(ws + OFF_AR1, 0, 65536, stream);

    prep_weights<<<2304, 256, 0, stream>>>(Wf1, Wi1, Wg1, Wo1, Wf2, Wi2, Wg2, Wo2,
                                           w1h, w1l, w2h, w2l);

    // Plain launch: 192 blocks (512 thr) < 256 CUs, 1 block/CU -> co-resident.
    lstm_seq<<<dim3(NBLK), dim3(512), 53776, stream>>>(
        x, bf1, bi1, bg1, bo1, bf2, bi2, bg2, bo2,
        gamma1, beta1, gamma2, beta2,
        w1h, w1l, w2h, w2l,
        h1x, h2x, a1, a2, dn2, regx,
        R, (float*)d_out);
}